// Round 2
// baseline (667.722 us; speedup 1.0000x reference)
//
#include <hip/hip_runtime.h>

#define HSZ 128
#define WSZ 128
#define HWSZ (HSZ*WSZ)      // 16384
#define NB 4
#define NBP 16
#define NPIX (NB*HWSZ)      // 65536

// ws layout (float offsets)
#define OFF_CM 0            // 64 floats: column-mean of pw_w
#define OFF_PBM 64          // 1 float: mean of pw_b
#define OFF_MB 128          // NPIX*4 floats = 1 MB: mask bias per (pixel, p)

typedef unsigned short u16;

__device__ __forceinline__ float bf2f(u16 u) {
    unsigned int x = ((unsigned int)u) << 16;
    return __uint_as_float(x);
}
__device__ __forceinline__ u16 f2bf_bits(float f) {
    unsigned int x = __float_as_uint(f);
    unsigned int r = x + 0x7fffu + ((x >> 16) & 1u);   // RNE
    return (u16)(r >> 16);
}

// ---------------- Kernel 0: colmean(pw_w), mean(pw_b) ----------------------
__global__ void prep_kernel(const float* __restrict__ pww,
                            const float* __restrict__ pwb,
                            float* __restrict__ ws) {
    int t = threadIdx.x;
    if (t < 64) {
        float s = 0.f;
        for (int co = 0; co < 64; ++co) s += pww[co*64 + t];
        ws[OFF_CM + t] = s * (1.0f/64.0f);
    }
    if (t == 0) {
        float s = 0.f;
        for (int i = 0; i < 64; ++i) s += pwb[i];
        ws[OFF_PBM] = s * (1.0f/64.0f);
    }
}

// ---------------- Kernel 1: mask branch -> mb[pix][p] ----------------------
// mb = colmean . gelu(dwconv3x3(mask)+dw_b) + mean(pw_b)
__global__ __launch_bounds__(256) void mask_kernel(const float* __restrict__ mask,
                                                   const float* __restrict__ dww,
                                                   const float* __restrict__ dwb,
                                                   float* __restrict__ ws) {
    int bid = blockIdx.x;          // 1024 blocks: [bp(16)][hpair(64)]
    int bp = bid >> 6;
    int hpair = bid & 63;
    int t = threadIdx.x;
    int h = hpair*2 + (t >> 7);
    int w = t & 127;
    const float* cm = ws + OFF_CM;
    const float* mbase = mask + (size_t)bp*64*HWSZ;
    float acc = 0.f;
    for (int c = 0; c < 64; ++c) {
        float s = dwb[c];
        #pragma unroll
        for (int dy = -1; dy <= 1; ++dy) {
            int h2 = h + dy;
            if (h2 < 0 || h2 >= HSZ) continue;
            #pragma unroll
            for (int dx = -1; dx <= 1; ++dx) {
                int w2 = w + dx;
                if (w2 < 0 || w2 >= WSZ) continue;
                s += dww[c*9 + (dy+1)*3 + (dx+1)] * mbase[c*HWSZ + h2*WSZ + w2];
            }
        }
        float g = 0.5f * s * (1.0f + erff(s * 0.70710678118654752f)); // exact GELU
        acc += cm[c] * g;
    }
    acc += ws[OFF_PBM];
    int b = bp >> 2, p = bp & 3;
    ws[OFF_MB + (size_t)(b*HWSZ + h*WSZ + w)*4 + p] = acc;
}

// ---------------- Kernel 2: fused qkv + attention + proj -------------------
// block = 256 thr = 64 pixels x 4 head-groups (2 heads each). x tile in LDS (bf16).
__global__ __launch_bounds__(256) void attn_kernel(const float* __restrict__ x_in,
                                                   const float* __restrict__ wq,
                                                   const float* __restrict__ wk,
                                                   const float* __restrict__ wv,
                                                   const float* __restrict__ wp,
                                                   const float* __restrict__ bpj,
                                                   const float* __restrict__ rsc,
                                                   const float* __restrict__ ws,
                                                   float* __restrict__ out) {
    __shared__ u16 x_sh[256*64];            // [p*64+c][pix] 32 KB (bf16)
    __shared__ unsigned int y_sh[128*64];   // [p*32+cpair][pix] 32 KB (bf16x2)
    int t = threadIdx.x;
    int pix0 = blockIdx.x * 64;
    int b = pix0 >> 14;
    int hw0 = pix0 & (HWSZ-1);

    // stage x: load fp32 pairs, round to bf16, pack. Coalesced along w.
    const float2* x2 = (const float2*)x_in;
    unsigned int* xs32 = (unsigned int*)x_sh;
    for (int i = t; i < 8192; i += 256) {
        int row = i >> 5, col = i & 31;     // row = p*64+c
        float2 v = x2[(size_t)(b*256 + row)*(HWSZ/2) + (hw0 >> 1) + col];
        xs32[i] = (unsigned int)f2bf_bits(v.x) | ((unsigned int)f2bf_bits(v.y) << 16);
    }
    __syncthreads();

    int pixloc = t & 63;
    int hg = __builtin_amdgcn_readfirstlane(t >> 6);  // wave-uniform head group
    int pixg = pix0 + pixloc;
    int hw = hw0 + pixloc;

    const float4 mb4 = *(const float4*)(ws + OFF_MB + (size_t)pixg*4);
    float mba[4] = {mb4.x, mb4.y, mb4.z, mb4.w};

    for (int hh = 0; hh < 2; ++hh) {
        int hd = hg*2 + hh;
        float q[4][8], k[4][8], v[4][8];
        #pragma unroll
        for (int p = 0; p < 4; ++p)
            #pragma unroll
            for (int j = 0; j < 8; ++j) { q[p][j]=0.f; k[p][j]=0.f; v[p][j]=0.f; }
        #pragma unroll
        for (int p = 0; p < 4; ++p) {
            for (int c = 0; c < 64; ++c) {
                float xv = bf2f(x_sh[(p*64+c)*64 + pixloc]);
                const float* wq_c = wq + hd*512 + c;   // uniform -> s_load
                const float* wk_c = wk + hd*512 + c;
                const float* wv_c = wv + hd*512 + c;
                #pragma unroll
                for (int j = 0; j < 8; ++j) {
                    q[p][j] = fmaf(wq_c[j*64], xv, q[p][j]);
                    k[p][j] = fmaf(wk_c[j*64], xv, k[p][j]);
                    v[p][j] = fmaf(wv_c[j*64], xv, v[p][j]);
                }
            }
        }
        // L2 normalize q,k over head dim (clamp_min(eps))
        #pragma unroll
        for (int p = 0; p < 4; ++p) {
            float sq = 0.f, sk = 0.f;
            #pragma unroll
            for (int j = 0; j < 8; ++j) { sq += q[p][j]*q[p][j]; sk += k[p][j]*k[p][j]; }
            float iq = 1.0f / fmaxf(sqrtf(sq), 1e-12f);
            float ik = 1.0f / fmaxf(sqrtf(sk), 1e-12f);
            #pragma unroll
            for (int j = 0; j < 8; ++j) { q[p][j] *= iq; k[p][j] *= ik; }
        }
        float rs = rsc[hd];
        float at[4][4];
        #pragma unroll
        for (int p = 0; p < 4; ++p) {
            #pragma unroll
            for (int r = 0; r < 4; ++r) {
                float d = 0.f;
                #pragma unroll
                for (int j = 0; j < 8; ++j) d += q[p][j]*k[r][j];
                at[p][r] = d*rs + (mba[r] - mba[p]);
            }
            float m = fmaxf(fmaxf(at[p][0], at[p][1]), fmaxf(at[p][2], at[p][3]));
            float e0 = expf(at[p][0]-m), e1 = expf(at[p][1]-m);
            float e2 = expf(at[p][2]-m), e3 = expf(at[p][3]-m);
            float inv = 1.0f / (e0+e1+e2+e3);
            at[p][0]=e0*inv; at[p][1]=e1*inv; at[p][2]=e2*inv; at[p][3]=e3*inv;
        }
        // y = at @ v, pack bf16x2 into LDS for proj phase
        #pragma unroll
        for (int p = 0; p < 4; ++p) {
            #pragma unroll
            for (int jp = 0; jp < 4; ++jp) {
                float y0 = 0.f, y1 = 0.f;
                #pragma unroll
                for (int r = 0; r < 4; ++r) {
                    y0 += at[p][r]*v[r][2*jp];
                    y1 += at[p][r]*v[r][2*jp+1];
                }
                unsigned int pk = (unsigned int)f2bf_bits(y0) |
                                  ((unsigned int)f2bf_bits(y1) << 16);
                y_sh[(p*32 + hd*4 + jp)*64 + pixloc] = pk;
            }
        }
    }
    __syncthreads();

    // proj: thread (pixloc, pp=hg) computes all 64 out channels for its (pix,p)
    int pp = hg;
    float yreg[64];
    #pragma unroll
    for (int cp = 0; cp < 32; ++cp) {
        unsigned int u = y_sh[(pp*32 + cp)*64 + pixloc];
        yreg[2*cp]   = bf2f((u16)(u & 0xffffu));
        yreg[2*cp+1] = bf2f((u16)(u >> 16));
    }
    for (int co = 0; co < 64; ++co) {
        float acc = bpj[co];
        #pragma unroll
        for (int ch = 0; ch < 64; ++ch) acc = fmaf(wp[co*64+ch], yreg[ch], acc);
        out[(size_t)(b*256 + pp*64 + co)*HWSZ + hw] = acc;
    }
}

extern "C" void kernel_launch(void* const* d_in, const int* in_sizes, int n_in,
                              void* d_out, int out_size, void* d_ws, size_t ws_size,
                              hipStream_t stream) {
    const float* x_in  = (const float*)d_in[0];
    const float* mask  = (const float*)d_in[1];
    const float* wq    = (const float*)d_in[2];
    const float* wk    = (const float*)d_in[3];
    const float* wv    = (const float*)d_in[4];
    const float* wproj = (const float*)d_in[5];
    const float* bproj = (const float*)d_in[6];
    const float* resc  = (const float*)d_in[7];
    const float* dww   = (const float*)d_in[8];
    const float* dwb   = (const float*)d_in[9];
    const float* pww   = (const float*)d_in[10];
    const float* pwb   = (const float*)d_in[11];
    float* ws = (float*)d_ws;
    float* outp = (float*)d_out;

    hipLaunchKernelGGL(prep_kernel, dim3(1), dim3(256), 0, stream, pww, pwb, ws);
    hipLaunchKernelGGL(mask_kernel, dim3(NBP * HSZ / 2), dim3(256), 0, stream,
                       mask, dww, dwb, ws);
    hipLaunchKernelGGL(attn_kernel, dim3(NPIX / 64), dim3(256), 0, stream,
                       x_in, wq, wk, wv, wproj, bproj, resc, ws, outp);
}

// Round 3
// 281.223 us; speedup vs baseline: 2.3743x; 2.3743x over previous
//
#include <hip/hip_runtime.h>

#define HSZ 128
#define WSZ 128
#define HWSZ (HSZ*WSZ)      // 16384
#define NB 4

// ws layout (float offsets)
#define OFF_CM 0            // 64 floats: column-mean of pw_w
#define OFF_PBM 64          // 1 float: mean of pw_b
#define OFF_MB 128          // NPIX*4 floats: mask bias per (pixel, p)

typedef unsigned short u16;
typedef __attribute__((ext_vector_type(8))) short bf16x8;
typedef __attribute__((ext_vector_type(4))) float f32x4;

__device__ __forceinline__ float bf2f(u16 u) {
    return __uint_as_float(((unsigned int)u) << 16);
}
__device__ __forceinline__ u16 f2bf_bits(float f) {
    unsigned int x = __float_as_uint(f);
    return (u16)((x + 0x7fffu + ((x >> 16) & 1u)) >> 16);   // RNE
}
__device__ __forceinline__ bf16x8 pack8(const float* s) {
    bf16x8 r;
    #pragma unroll
    for (int j = 0; j < 8; ++j) r[j] = (short)f2bf_bits(s[j]);
    return r;
}
// lane's B-fragment: W[drow][k0..k0+7] as bf16 (B[k][n] with n=lane&15, k=quad*8+j)
__device__ __forceinline__ bf16x8 load_bfrag(const float* W, int drow, int k0) {
    float4 a = *(const float4*)(W + drow*64 + k0);
    float4 b = *(const float4*)(W + drow*64 + k0 + 4);
    float t[8] = {a.x,a.y,a.z,a.w,b.x,b.y,b.z,b.w};
    return pack8(t);
}

// ---------------- Kernel 0: colmean(pw_w), mean(pw_b) ----------------------
__global__ void prep_kernel(const float* __restrict__ pww,
                            const float* __restrict__ pwb,
                            float* __restrict__ ws) {
    int t = threadIdx.x;
    if (t < 64) {
        float s = 0.f;
        for (int co = 0; co < 64; ++co) s += pww[co*64 + t];
        ws[OFF_CM + t] = s * (1.0f/64.0f);
    }
    if (t == 0) {
        float s = 0.f;
        for (int i = 0; i < 64; ++i) s += pwb[i];
        ws[OFF_PBM] = s * (1.0f/64.0f);
    }
}

// ---------------- Kernel 1: mask branch -> mb[pix][p] ----------------------
// mb = colmean . gelu(dwconv3x3(mask)+dw_b) + mean(pw_b). Branch-free,
// 4 pixels/thread (float4 center loads), zero-weight border handling.
__global__ __launch_bounds__(256) void mask_kernel(const float* __restrict__ mask,
                                                   const float* __restrict__ dww,
                                                   const float* __restrict__ dwb,
                                                   float* __restrict__ ws) {
    int bid = blockIdx.x;          // 256 blocks: [bp(16)][hgroup(16)]
    int bp = bid >> 4;
    int hg = bid & 15;
    int t = threadIdx.x;           // 256 thr = 8 rows x 32 colgroups
    int h = hg*8 + (t >> 5);
    int w0 = (t & 31) << 2;
    const float* mb_ = mask + (size_t)bp*64*HWSZ;
    int hm = h > 0 ? h-1 : 0;
    int hp = h < 127 ? h+1 : 127;
    float vt = h > 0 ? 1.f : 0.f;
    float vb = h < 127 ? 1.f : 0.f;
    float vl = w0 > 0 ? 1.f : 0.f;
    float vr = w0 < 124 ? 1.f : 0.f;
    int wl = w0 > 0 ? w0-1 : 0;
    int wr = w0 < 124 ? w0+4 : 127;
    const float* cm = ws + OFF_CM;
    float acc0=0.f, acc1=0.f, acc2=0.f, acc3=0.f;
    for (int c = 0; c < 64; ++c) {
        const float* rc = mb_ + c*HWSZ;
        const float* r0 = rc + hm*WSZ;
        const float* r1 = rc + h*WSZ;
        const float* r2 = rc + hp*WSZ;
        float4 m0 = *(const float4*)(r0 + w0);
        float4 m1 = *(const float4*)(r1 + w0);
        float4 m2 = *(const float4*)(r2 + w0);
        float L0 = r0[wl]*vl, L1 = r1[wl]*vl, L2 = r2[wl]*vl;
        float R0 = r0[wr]*vr, R1 = r1[wr]*vr, R2 = r2[wr]*vr;
        float w00 = dww[c*9+0]*vt, w01 = dww[c*9+1]*vt, w02 = dww[c*9+2]*vt;
        float w10 = dww[c*9+3],    w11 = dww[c*9+4],    w12 = dww[c*9+5];
        float w20 = dww[c*9+6]*vb, w21 = dww[c*9+7]*vb, w22 = dww[c*9+8]*vb;
        float bb = dwb[c];
        float s0 = bb + w00*L0   + w01*m0.x + w02*m0.y
                      + w10*L1   + w11*m1.x + w12*m1.y
                      + w20*L2   + w21*m2.x + w22*m2.y;
        float s1 = bb + w00*m0.x + w01*m0.y + w02*m0.z
                      + w10*m1.x + w11*m1.y + w12*m1.z
                      + w20*m2.x + w21*m2.y + w22*m2.z;
        float s2 = bb + w00*m0.y + w01*m0.z + w02*m0.w
                      + w10*m1.y + w11*m1.z + w12*m1.w
                      + w20*m2.y + w21*m2.z + w22*m2.w;
        float s3 = bb + w00*m0.z + w01*m0.w + w02*R0
                      + w10*m1.z + w11*m1.w + w12*R1
                      + w20*m2.z + w21*m2.w + w22*R2;
        float cmc = cm[c];
        acc0 += cmc * (0.5f*s0*(1.f + erff(s0*0.70710678118654752f)));
        acc1 += cmc * (0.5f*s1*(1.f + erff(s1*0.70710678118654752f)));
        acc2 += cmc * (0.5f*s2*(1.f + erff(s2*0.70710678118654752f)));
        acc3 += cmc * (0.5f*s3*(1.f + erff(s3*0.70710678118654752f)));
    }
    float pbm = ws[OFF_PBM];
    int b = bp >> 2, p = bp & 3;
    size_t base = (size_t)b*HWSZ + h*WSZ + w0;
    ws[OFF_MB + (base+0)*4 + p] = acc0 + pbm;
    ws[OFF_MB + (base+1)*4 + p] = acc1 + pbm;
    ws[OFF_MB + (base+2)*4 + p] = acc2 + pbm;
    ws[OFF_MB + (base+3)*4 + p] = acc3 + pbm;
}

// ---------------- Kernel 2: MFMA qkv + attention + MFMA proj ---------------
// Block = 256 thr (4 waves), 32 pixels = 128 tokens (tau = p*32+pix).
// Phase1: Q/K/V = X*W^T via mfma_f32_16x16x32_bf16, wave w owns d-quarter w.
// Phase2: 1 thread = 1 (pix,head): normalize, 4x4 scores+softmax(+mb[r]), PV.
// Phase3: out = Y*Wp^T + b via MFMA, transpose through XOR-swizzled LDS.
__global__ __launch_bounds__(256) void attn_kernel(const float* __restrict__ x_in,
                                                   const float* __restrict__ wq,
                                                   const float* __restrict__ wk,
                                                   const float* __restrict__ wv,
                                                   const float* __restrict__ wp,
                                                   const float* __restrict__ bpj,
                                                   const float* __restrict__ rsc,
                                                   const float* __restrict__ ws,
                                                   float* __restrict__ out) {
    __shared__ u16 smem[32768];           // 64 KB
    u16* ldsA = smem;                     // 16 KB: x then y, A-frag order
    u16* ldsQ = smem + 8192;              // 16 KB: [mt][dt][row16][col16]
    u16* ldsK = smem + 16384;
    u16* ldsV = smem + 24576;
    float* outS = (float*)(smem + 8192);  // 32 KB fp32, overlays Q,K (phase 3)

    int t = threadIdx.x;
    int lane = t & 63;
    int wid = __builtin_amdgcn_readfirstlane(t >> 6);
    int n15 = lane & 15;
    int quad = lane >> 4;
    int b = blockIdx.x >> 9;              // 2048 blocks = 4 b x 512
    int hw0 = (blockIdx.x & 511) << 5;

    // B-fragments (bf16) for this wave's d-quarter
    bf16x8 fq0 = load_bfrag(wq, wid*16 + n15, quad*8);
    bf16x8 fq1 = load_bfrag(wq, wid*16 + n15, 32 + quad*8);
    bf16x8 fk0 = load_bfrag(wk, wid*16 + n15, quad*8);
    bf16x8 fk1 = load_bfrag(wk, wid*16 + n15, 32 + quad*8);
    bf16x8 fv0 = load_bfrag(wv, wid*16 + n15, quad*8);
    bf16x8 fv1 = load_bfrag(wv, wid*16 + n15, 32 + quad*8);
    bf16x8 fp0 = load_bfrag(wp, wid*16 + n15, quad*8);
    bf16x8 fp1 = load_bfrag(wp, wid*16 + n15, 32 + quad*8);
    float bias = bpj[wid*16 + n15];

    // stage x -> ldsA in A-frag order: frag(mt,kt): lane slot holds
    // X[mt*16+(lane&15)][kt*32+(lane>>4)*8+j], j=0..7
    for (int it = 0; it < 8; ++it) {
        int i = t + (it << 8);            // 0..2047 float4 loads
        int row = i >> 3;                 // p*64+c (global row order)
        int l4 = i & 7;
        float4 xv = *(const float4*)(x_in + (size_t)(b*256 + row)*HWSZ + hw0 + l4*4);
        int p = row >> 6, c = row & 63;
        int kt = c >> 5, qd = (c >> 3) & 3, j = c & 7;
        float vals[4] = {xv.x, xv.y, xv.z, xv.w};
        #pragma unroll
        for (int e = 0; e < 4; ++e) {
            int tau = (p << 5) + (l4 << 2) + e;
            int slot = (tau & 15) | (qd << 4);
            ldsA[((tau >> 4)*2 + kt)*512 + slot*8 + j] = f2bf_bits(vals[e]);
        }
    }
    __syncthreads();

    // ---- phase 1: Q,K,V GEMMs ----
    for (int mt = 0; mt < 8; ++mt) {
        bf16x8 a0 = *(const bf16x8*)(ldsA + mt*1024 + lane*8);
        bf16x8 a1 = *(const bf16x8*)(ldsA + mt*1024 + 512 + lane*8);
        f32x4 aq = {0.f,0.f,0.f,0.f};
        f32x4 ak = {0.f,0.f,0.f,0.f};
        f32x4 av = {0.f,0.f,0.f,0.f};
        aq = __builtin_amdgcn_mfma_f32_16x16x32_bf16(a0, fq0, aq, 0, 0, 0);
        aq = __builtin_amdgcn_mfma_f32_16x16x32_bf16(a1, fq1, aq, 0, 0, 0);
        ak = __builtin_amdgcn_mfma_f32_16x16x32_bf16(a0, fk0, ak, 0, 0, 0);
        ak = __builtin_amdgcn_mfma_f32_16x16x32_bf16(a1, fk1, ak, 0, 0, 0);
        av = __builtin_amdgcn_mfma_f32_16x16x32_bf16(a0, fv0, av, 0, 0, 0);
        av = __builtin_amdgcn_mfma_f32_16x16x32_bf16(a1, fv1, av, 0, 0, 0);
        int cb = (mt*4 + wid)*256 + n15;  // C: col=lane&15, row=quad*4+reg
        #pragma unroll
        for (int r = 0; r < 4; ++r) {
            int rl = (quad*4 + r)*16;
            ldsQ[cb + rl] = f2bf_bits(aq[r]);
            ldsK[cb + rl] = f2bf_bits(ak[r]);
            ldsV[cb + rl] = f2bf_bits(av[r]);
        }
    }
    __syncthreads();

    // ---- phase 2: attention core (1 thread = 1 (pix, head)) ----
    {
        int pix = t & 31;
        int hd = t >> 5;
        float qv[4][8], kv[4][8], vv[4][8];
        #pragma unroll
        for (int p = 0; p < 4; ++p) {
            int tau = (p << 5) + pix;
            int base = ((tau >> 4)*4 + (hd >> 1))*256 + (tau & 15)*16 + (hd & 1)*8;
            bf16x8 q8 = *(const bf16x8*)(ldsQ + base);
            bf16x8 k8 = *(const bf16x8*)(ldsK + base);
            bf16x8 v8 = *(const bf16x8*)(ldsV + base);
            #pragma unroll
            for (int j = 0; j < 8; ++j) {
                qv[p][j] = bf2f((u16)q8[j]);
                kv[p][j] = bf2f((u16)k8[j]);
                vv[p][j] = bf2f((u16)v8[j]);
            }
        }
        #pragma unroll
        for (int p = 0; p < 4; ++p) {
            float sq = 0.f, sk = 0.f;
            #pragma unroll
            for (int j = 0; j < 8; ++j) { sq += qv[p][j]*qv[p][j]; sk += kv[p][j]*kv[p][j]; }
            float iq = 1.0f / fmaxf(sqrtf(sq), 1e-12f);
            float ik = 1.0f / fmaxf(sqrtf(sk), 1e-12f);
            #pragma unroll
            for (int j = 0; j < 8; ++j) { qv[p][j] *= iq; kv[p][j] *= ik; }
        }
        float4 mb4 = *(const float4*)(ws + OFF_MB + ((size_t)b*HWSZ + hw0 + pix)*4);
        float mba[4] = {mb4.x, mb4.y, mb4.z, mb4.w};
        float rs = rsc[hd];
        float at[4][4];
        #pragma unroll
        for (int p = 0; p < 4; ++p) {
            #pragma unroll
            for (int r = 0; r < 4; ++r) {
                float d = 0.f;
                #pragma unroll
                for (int j = 0; j < 8; ++j) d += qv[p][j]*kv[r][j];
                at[p][r] = d*rs + mba[r];   // -mb[p] cancels in softmax
            }
            float m = fmaxf(fmaxf(at[p][0], at[p][1]), fmaxf(at[p][2], at[p][3]));
            float e0 = expf(at[p][0]-m), e1 = expf(at[p][1]-m);
            float e2 = expf(at[p][2]-m), e3 = expf(at[p][3]-m);
            float inv = 1.0f / (e0+e1+e2+e3);
            at[p][0]=e0*inv; at[p][1]=e1*inv; at[p][2]=e2*inv; at[p][3]=e3*inv;
        }
        #pragma unroll
        for (int p = 0; p < 4; ++p) {
            float y[8];
            #pragma unroll
            for (int j = 0; j < 8; ++j) {
                y[j] = at[p][0]*vv[0][j] + at[p][1]*vv[1][j]
                     + at[p][2]*vv[2][j] + at[p][3]*vv[3][j];
            }
            int tau = (p << 5) + pix;      // y -> ldsA in A-frag order (d=hd*8+j)
            int idx = ((tau >> 4)*2 + (hd >> 2))*512 + ((tau & 15) + ((hd & 3) << 4))*8;
            *(bf16x8*)(ldsA + idx) = pack8(y);
        }
    }
    __syncthreads();

    // ---- phase 3: proj GEMM + bias, transpose via swizzled LDS ----
    for (int mt = 0; mt < 8; ++mt) {
        bf16x8 a0 = *(const bf16x8*)(ldsA + mt*1024 + lane*8);
        bf16x8 a1 = *(const bf16x8*)(ldsA + mt*1024 + 512 + lane*8);
        f32x4 ao = {0.f,0.f,0.f,0.f};
        ao = __builtin_amdgcn_mfma_f32_16x16x32_bf16(a0, fp0, ao, 0, 0, 0);
        ao = __builtin_amdgcn_mfma_f32_16x16x32_bf16(a1, fp1, ao, 0, 0, 0);
        #pragma unroll
        for (int r = 0; r < 4; ++r) {
            int tau = mt*16 + quad*4 + r;
            int d = wid*16 + n15;
            outS[tau*64 + (d ^ (tau & 31))] = ao[r] + bias;
        }
    }
    __syncthreads();
    for (int g = 0; g < 32; ++g) {
        int flat = (g << 8) + t;
        int px = flat & 31;
        int pd = flat >> 5;
        int d = pd & 63;
        int p = pd >> 6;
        int tau = (p << 5) + px;
        out[(size_t)((b*4 + p)*64 + d)*HWSZ + hw0 + px] = outS[tau*64 + (d ^ (tau & 31))];
    }
}

extern "C" void kernel_launch(void* const* d_in, const int* in_sizes, int n_in,
                              void* d_out, int out_size, void* d_ws, size_t ws_size,
                              hipStream_t stream) {
    const float* x_in  = (const float*)d_in[0];
    const float* mask  = (const float*)d_in[1];
    const float* wq    = (const float*)d_in[2];
    const float* wk    = (const float*)d_in[3];
    const float* wv    = (const float*)d_in[4];
    const float* wproj = (const float*)d_in[5];
    const float* bproj = (const float*)d_in[6];
    const float* resc  = (const float*)d_in[7];
    const float* dww   = (const float*)d_in[8];
    const float* dwb   = (const float*)d_in[9];
    const float* pww   = (const float*)d_in[10];
    const float* pwb   = (const float*)d_in[11];
    float* ws = (float*)d_ws;
    float* outp = (float*)d_out;

    hipLaunchKernelGGL(prep_kernel, dim3(1), dim3(256), 0, stream, pww, pwb, ws);
    hipLaunchKernelGGL(mask_kernel, dim3(256), dim3(256), 0, stream,
                       mask, dww, dwb, ws);
    hipLaunchKernelGGL(attn_kernel, dim3(2048), dim3(256), 0, stream,
                       x_in, wq, wk, wv, wproj, bproj, resc, ws, outp);
}

// Round 4
// 240.228 us; speedup vs baseline: 2.7795x; 1.1707x over previous
//
#include <hip/hip_runtime.h>

#define HSZ 128
#define WSZ 128
#define HWSZ (HSZ*WSZ)      // 16384
#define NB 4

// ws layout (float offsets)
#define OFF_CM 0            // 64 floats: column-mean of pw_w
#define OFF_MB 128          // NPIX*4 floats: mask bias per (pixel, p)

typedef unsigned short u16;
typedef __attribute__((ext_vector_type(8))) short bf16x8;
typedef __attribute__((ext_vector_type(4))) float f32x4;

__device__ __forceinline__ float bf2f(u16 u) {
    return __uint_as_float(((unsigned int)u) << 16);
}
__device__ __forceinline__ u16 f2bf_bits(float f) {
    unsigned int x = __float_as_uint(f);
    return (u16)((x + 0x7fffu + ((x >> 16) & 1u)) >> 16);   // RNE
}
__device__ __forceinline__ bf16x8 pack8(const float* s) {
    bf16x8 r;
    #pragma unroll
    for (int j = 0; j < 8; ++j) r[j] = (short)f2bf_bits(s[j]);
    return r;
}
// lane's B-fragment: W[drow][k0..k0+7] as bf16 (B[k][n] with n=lane&15, k=quad*8+j)
__device__ __forceinline__ bf16x8 load_bfrag(const float* W, int drow, int k0) {
    float4 a = *(const float4*)(W + drow*64 + k0);
    float4 b = *(const float4*)(W + drow*64 + k0 + 4);
    float t[8] = {a.x,a.y,a.z,a.w,b.x,b.y,b.z,b.w};
    return pack8(t);
}

// ---------------- Kernel 0: colmean(pw_w) ----------------------------------
__global__ void prep_kernel(const float* __restrict__ pww,
                            float* __restrict__ ws) {
    int t = threadIdx.x;
    if (t < 64) {
        float s = 0.f;
        for (int co = 0; co < 64; ++co) s += pww[co*64 + t];
        ws[OFF_CM + t] = s * (1.0f/64.0f);
    }
}

// ---------------- Kernel 1: mask branch -> mb[pix][p] ----------------------
// mb = colmean . gelu(dwconv3x3(mask)+dw_b)   (mean(pw_b) cancels in softmax)
// 1024 thr = 4 channel-quarters x 256 pixel-slots; LDS reduce over quarters.
__global__ __launch_bounds__(1024) void mask_kernel(const float* __restrict__ mask,
                                                    const float* __restrict__ dww,
                                                    const float* __restrict__ dwb,
                                                    float* __restrict__ ws) {
    __shared__ float red[4][256][4];   // 16 KB
    int bid = blockIdx.x;              // 256 blocks: [bp(16)][hgroup(16)]
    int bp = bid >> 4;
    int hg = bid & 15;
    int tid = threadIdx.x;
    int cq = tid >> 8;                 // channel quarter 0..3
    int t = tid & 255;                 // pixel slot: 8 rows x 32 colgroups
    int h = hg*8 + (t >> 5);
    int w0 = (t & 31) << 2;
    const float* mb_ = mask + (size_t)bp*64*HWSZ;
    int hm = h > 0 ? h-1 : 0;
    int hp = h < 127 ? h+1 : 127;
    float vt = h > 0 ? 1.f : 0.f;
    float vb = h < 127 ? 1.f : 0.f;
    float vl = w0 > 0 ? 1.f : 0.f;
    float vr = w0 < 124 ? 1.f : 0.f;
    int wl = w0 > 0 ? w0-1 : 0;
    int wr = w0 < 124 ? w0+4 : 127;
    const float* cm = ws + OFF_CM;
    float acc0=0.f, acc1=0.f, acc2=0.f, acc3=0.f;
    for (int ci = 0; ci < 16; ++ci) {
        int c = cq*16 + ci;
        const float* rc = mb_ + c*HWSZ;
        const float* r0 = rc + hm*WSZ;
        const float* r1 = rc + h*WSZ;
        const float* r2 = rc + hp*WSZ;
        float4 m0 = *(const float4*)(r0 + w0);
        float4 m1 = *(const float4*)(r1 + w0);
        float4 m2 = *(const float4*)(r2 + w0);
        float L0 = r0[wl]*vl, L1 = r1[wl]*vl, L2 = r2[wl]*vl;
        float R0 = r0[wr]*vr, R1 = r1[wr]*vr, R2 = r2[wr]*vr;
        float w00 = dww[c*9+0]*vt, w01 = dww[c*9+1]*vt, w02 = dww[c*9+2]*vt;
        float w10 = dww[c*9+3],    w11 = dww[c*9+4],    w12 = dww[c*9+5];
        float w20 = dww[c*9+6]*vb, w21 = dww[c*9+7]*vb, w22 = dww[c*9+8]*vb;
        float bb = dwb[c];
        float s0 = bb + w00*L0   + w01*m0.x + w02*m0.y
                      + w10*L1   + w11*m1.x + w12*m1.y
                      + w20*L2   + w21*m2.x + w22*m2.y;
        float s1 = bb + w00*m0.x + w01*m0.y + w02*m0.z
                      + w10*m1.x + w11*m1.y + w12*m1.z
                      + w20*m2.x + w21*m2.y + w22*m2.z;
        float s2 = bb + w00*m0.y + w01*m0.z + w02*m0.w
                      + w10*m1.y + w11*m1.z + w12*m1.w
                      + w20*m2.y + w21*m2.z + w22*m2.w;
        float s3 = bb + w00*m0.z + w01*m0.w + w02*R0
                      + w10*m1.z + w11*m1.w + w12*R1
                      + w20*m2.z + w21*m2.w + w22*R2;
        float cmc = cm[c];
        acc0 += cmc * (0.5f*s0*(1.f + erff(s0*0.70710678118654752f)));
        acc1 += cmc * (0.5f*s1*(1.f + erff(s1*0.70710678118654752f)));
        acc2 += cmc * (0.5f*s2*(1.f + erff(s2*0.70710678118654752f)));
        acc3 += cmc * (0.5f*s3*(1.f + erff(s3*0.70710678118654752f)));
    }
    red[cq][t][0] = acc0;
    red[cq][t][1] = acc1;
    red[cq][t][2] = acc2;
    red[cq][t][3] = acc3;
    __syncthreads();
    if (tid < 256) {
        int b = bp >> 2, p = bp & 3;
        size_t base = (size_t)b*HWSZ + h*WSZ + w0;
        #pragma unroll
        for (int e = 0; e < 4; ++e) {
            float v = red[0][tid][e] + red[1][tid][e] + red[2][tid][e] + red[3][tid][e];
            ws[OFF_MB + (base+e)*4 + p] = v;
        }
    }
}

// ---------------- Kernel 2: MFMA qkv + attention + MFMA proj ---------------
// Block = 256 thr (4 waves), 32 pixels = 128 tokens (tau = p*32+pix).
// Phase1: Q/K/V = X*W^T via mfma_f32_16x16x32_bf16, wave w owns d-quarter w.
// Phase2: 1 thread = 1 (pix,head): normalize, 4x4 scores+softmax(+mb[r]), PV.
// Phase3: out = Y*Wp^T + b via MFMA, transpose through XOR-swizzled LDS.
__global__ __launch_bounds__(256) void attn_kernel(const float* __restrict__ x_in,
                                                   const float* __restrict__ wq,
                                                   const float* __restrict__ wk,
                                                   const float* __restrict__ wv,
                                                   const float* __restrict__ wp,
                                                   const float* __restrict__ bpj,
                                                   const float* __restrict__ rsc,
                                                   const float* __restrict__ ws,
                                                   float* __restrict__ out) {
    __shared__ u16 smem[32768];           // 64 KB
    u16* ldsA = smem;                     // 16 KB: x then y, A-frag order
    u16* ldsQ = smem + 8192;              // 16 KB: [mt][dt][row16][col16]
    u16* ldsK = smem + 16384;
    u16* ldsV = smem + 24576;
    float* outS = (float*)(smem + 8192);  // 32 KB fp32, overlays Q,K (phase 3)

    int t = threadIdx.x;
    int lane = t & 63;
    int wid = __builtin_amdgcn_readfirstlane(t >> 6);
    int n15 = lane & 15;
    int quad = lane >> 4;
    int b = blockIdx.x >> 9;              // 2048 blocks = 4 b x 512
    int hw0 = (blockIdx.x & 511) << 5;

    // B-fragments (bf16) for this wave's d-quarter
    bf16x8 fq0 = load_bfrag(wq, wid*16 + n15, quad*8);
    bf16x8 fq1 = load_bfrag(wq, wid*16 + n15, 32 + quad*8);
    bf16x8 fk0 = load_bfrag(wk, wid*16 + n15, quad*8);
    bf16x8 fk1 = load_bfrag(wk, wid*16 + n15, 32 + quad*8);
    bf16x8 fv0 = load_bfrag(wv, wid*16 + n15, quad*8);
    bf16x8 fv1 = load_bfrag(wv, wid*16 + n15, 32 + quad*8);
    bf16x8 fp0 = load_bfrag(wp, wid*16 + n15, quad*8);
    bf16x8 fp1 = load_bfrag(wp, wid*16 + n15, 32 + quad*8);
    float bias = bpj[wid*16 + n15];

    // stage x -> ldsA in A-frag order: frag(mt,kt): lane slot holds
    // X[mt*16+(lane&15)][kt*32+(lane>>4)*8+j], j=0..7
    for (int it = 0; it < 8; ++it) {
        int i = t + (it << 8);            // 0..2047 float4 loads
        int row = i >> 3;                 // p*64+c (global row order)
        int l4 = i & 7;
        float4 xv = *(const float4*)(x_in + (size_t)(b*256 + row)*HWSZ + hw0 + l4*4);
        int p = row >> 6, c = row & 63;
        int kt = c >> 5, qd = (c >> 3) & 3, j = c & 7;
        float vals[4] = {xv.x, xv.y, xv.z, xv.w};
        #pragma unroll
        for (int e = 0; e < 4; ++e) {
            int tau = (p << 5) + (l4 << 2) + e;
            int slot = (tau & 15) | (qd << 4);
            ldsA[((tau >> 4)*2 + kt)*512 + slot*8 + j] = f2bf_bits(vals[e]);
        }
    }
    __syncthreads();

    // ---- phase 1: Q,K,V GEMMs ----
    for (int mt = 0; mt < 8; ++mt) {
        bf16x8 a0 = *(const bf16x8*)(ldsA + mt*1024 + lane*8);
        bf16x8 a1 = *(const bf16x8*)(ldsA + mt*1024 + 512 + lane*8);
        f32x4 aq = {0.f,0.f,0.f,0.f};
        f32x4 ak = {0.f,0.f,0.f,0.f};
        f32x4 av = {0.f,0.f,0.f,0.f};
        aq = __builtin_amdgcn_mfma_f32_16x16x32_bf16(a0, fq0, aq, 0, 0, 0);
        aq = __builtin_amdgcn_mfma_f32_16x16x32_bf16(a1, fq1, aq, 0, 0, 0);
        ak = __builtin_amdgcn_mfma_f32_16x16x32_bf16(a0, fk0, ak, 0, 0, 0);
        ak = __builtin_amdgcn_mfma_f32_16x16x32_bf16(a1, fk1, ak, 0, 0, 0);
        av = __builtin_amdgcn_mfma_f32_16x16x32_bf16(a0, fv0, av, 0, 0, 0);
        av = __builtin_amdgcn_mfma_f32_16x16x32_bf16(a1, fv1, av, 0, 0, 0);
        int cb = (mt*4 + wid)*256 + n15;  // C: col=lane&15, row=quad*4+reg
        #pragma unroll
        for (int r = 0; r < 4; ++r) {
            int rl = (quad*4 + r)*16;
            ldsQ[cb + rl] = f2bf_bits(aq[r]);
            ldsK[cb + rl] = f2bf_bits(ak[r]);
            ldsV[cb + rl] = f2bf_bits(av[r]);
        }
    }
    __syncthreads();

    // ---- phase 2: attention core (1 thread = 1 (pix, head)) ----
    {
        int pix = t & 31;
        int hd = t >> 5;
        float qv[4][8], kv[4][8], vv[4][8];
        #pragma unroll
        for (int p = 0; p < 4; ++p) {
            int tau = (p << 5) + pix;
            int base = ((tau >> 4)*4 + (hd >> 1))*256 + (tau & 15)*16 + (hd & 1)*8;
            bf16x8 q8 = *(const bf16x8*)(ldsQ + base);
            bf16x8 k8 = *(const bf16x8*)(ldsK + base);
            bf16x8 v8 = *(const bf16x8*)(ldsV + base);
            #pragma unroll
            for (int j = 0; j < 8; ++j) {
                qv[p][j] = bf2f((u16)q8[j]);
                kv[p][j] = bf2f((u16)k8[j]);
                vv[p][j] = bf2f((u16)v8[j]);
            }
        }
        #pragma unroll
        for (int p = 0; p < 4; ++p) {
            float sq = 0.f, sk = 0.f;
            #pragma unroll
            for (int j = 0; j < 8; ++j) { sq += qv[p][j]*qv[p][j]; sk += kv[p][j]*kv[p][j]; }
            float iq = 1.0f / fmaxf(sqrtf(sq), 1e-12f);
            float ik = 1.0f / fmaxf(sqrtf(sk), 1e-12f);
            #pragma unroll
            for (int j = 0; j < 8; ++j) { qv[p][j] *= iq; kv[p][j] *= ik; }
        }
        float4 mb4 = *(const float4*)(ws + OFF_MB + ((size_t)b*HWSZ + hw0 + pix)*4);
        float mba[4] = {mb4.x, mb4.y, mb4.z, mb4.w};
        float rs = rsc[hd];
        float at[4][4];
        #pragma unroll
        for (int p = 0; p < 4; ++p) {
            #pragma unroll
            for (int r = 0; r < 4; ++r) {
                float d = 0.f;
                #pragma unroll
                for (int j = 0; j < 8; ++j) d += qv[p][j]*kv[r][j];
                at[p][r] = d*rs + mba[r];   // -mb[p] cancels in softmax
            }
            float m = fmaxf(fmaxf(at[p][0], at[p][1]), fmaxf(at[p][2], at[p][3]));
            float e0 = expf(at[p][0]-m), e1 = expf(at[p][1]-m);
            float e2 = expf(at[p][2]-m), e3 = expf(at[p][3]-m);
            float inv = 1.0f / (e0+e1+e2+e3);
            at[p][0]=e0*inv; at[p][1]=e1*inv; at[p][2]=e2*inv; at[p][3]=e3*inv;
        }
        #pragma unroll
        for (int p = 0; p < 4; ++p) {
            float y[8];
            #pragma unroll
            for (int j = 0; j < 8; ++j) {
                y[j] = at[p][0]*vv[0][j] + at[p][1]*vv[1][j]
                     + at[p][2]*vv[2][j] + at[p][3]*vv[3][j];
            }
            int tau = (p << 5) + pix;      // y -> ldsA in A-frag order (d=hd*8+j)
            int idx = ((tau >> 4)*2 + (hd >> 2))*512 + ((tau & 15) + ((hd & 3) << 4))*8;
            *(bf16x8*)(ldsA + idx) = pack8(y);
        }
    }
    __syncthreads();

    // ---- phase 3: proj GEMM + bias, transpose via swizzled LDS ----
    for (int mt = 0; mt < 8; ++mt) {
        bf16x8 a0 = *(const bf16x8*)(ldsA + mt*1024 + lane*8);
        bf16x8 a1 = *(const bf16x8*)(ldsA + mt*1024 + 512 + lane*8);
        f32x4 ao = {0.f,0.f,0.f,0.f};
        ao = __builtin_amdgcn_mfma_f32_16x16x32_bf16(a0, fp0, ao, 0, 0, 0);
        ao = __builtin_amdgcn_mfma_f32_16x16x32_bf16(a1, fp1, ao, 0, 0, 0);
        #pragma unroll
        for (int r = 0; r < 4; ++r) {
            int tau = mt*16 + quad*4 + r;
            int d = wid*16 + n15;
            outS[tau*64 + (d ^ (tau & 31))] = ao[r] + bias;
        }
    }
    __syncthreads();
    for (int g = 0; g < 32; ++g) {
        int flat = (g << 8) + t;
        int px = flat & 31;
        int pd = flat >> 5;
        int d = pd & 63;
        int p = pd >> 6;
        int tau = (p << 5) + px;
        out[(size_t)((b*4 + p)*64 + d)*HWSZ + hw0 + px] = outS[tau*64 + (d ^ (tau & 31))];
    }
}

extern "C" void kernel_launch(void* const* d_in, const int* in_sizes, int n_in,
                              void* d_out, int out_size, void* d_ws, size_t ws_size,
                              hipStream_t stream) {
    const float* x_in  = (const float*)d_in[0];
    const float* mask  = (const float*)d_in[1];
    const float* wq    = (const float*)d_in[2];
    const float* wk    = (const float*)d_in[3];
    const float* wv    = (const float*)d_in[4];
    const float* wproj = (const float*)d_in[5];
    const float* bproj = (const float*)d_in[6];
    const float* resc  = (const float*)d_in[7];
    const float* dww   = (const float*)d_in[8];
    const float* dwb   = (const float*)d_in[9];
    const float* pww   = (const float*)d_in[10];
    float* ws = (float*)d_ws;
    float* outp = (float*)d_out;

    hipLaunchKernelGGL(prep_kernel, dim3(1), dim3(64), 0, stream, pww, ws);
    hipLaunchKernelGGL(mask_kernel, dim3(256), dim3(1024), 0, stream,
                       mask, dww, dwb, ws);
    hipLaunchKernelGGL(attn_kernel, dim3(2048), dim3(256), 0, stream,
                       x_in, wq, wk, wv, wproj, bproj, resc, ws, outp);
}

// Round 5
// 234.693 us; speedup vs baseline: 2.8451x; 1.0236x over previous
//
#include <hip/hip_runtime.h>
#include <hip/hip_bf16.h>

#define HSZ 128
#define WSZ 128
#define HWSZ (HSZ*WSZ)      // 16384
#define NB 4

// ws layout (float offsets)
#define OFF_MB 0            // NPIX*4 floats: mask bias per (pixel, p)

typedef unsigned short u16;
typedef __attribute__((ext_vector_type(8))) short bf16x8;
typedef __attribute__((ext_vector_type(4))) float f32x4;

__device__ __forceinline__ float bf2f(u16 u) {
    return __uint_as_float(((unsigned int)u) << 16);
}
// packed fp32x2 -> bf16x2 (v_cvt_pk_bf16_f32 on gfx950), RNE
__device__ __forceinline__ unsigned int cvt_pk_bf16(float lo, float hi) {
    __hip_bfloat162 h = __float22bfloat162_rn(make_float2(lo, hi));
    return *(unsigned int*)&h;
}
__device__ __forceinline__ u16 f2bf_bits(float f) {
    unsigned int x = __float_as_uint(f);
    return (u16)((x + 0x7fffu + ((x >> 16) & 1u)) >> 16);
}
// A-frag slot swizzle: bijective on 0..63, spreads 16B slot starts over banks
__device__ __forceinline__ int sswz(int s) { return s ^ (s >> 3); }
// QKV tile index: conflict-free store banking, b128-aligned reads
__device__ __forceinline__ int qkv_idx(int t, int d) {
    return (t >> 2)*64 + ((((t & 3) + (t >> 2)) & 3) << 4) + d;
}
// lane's B-fragment: W[drow][k0..k0+7] as bf16 (B[k][n] with n=lane&15, k=quad*8+j)
__device__ __forceinline__ bf16x8 load_bfrag(const float* W, int drow, int k0) {
    float4 a = *(const float4*)(W + drow*64 + k0);
    float4 b = *(const float4*)(W + drow*64 + k0 + 4);
    unsigned int u[4];
    u[0] = cvt_pk_bf16(a.x, a.y); u[1] = cvt_pk_bf16(a.z, a.w);
    u[2] = cvt_pk_bf16(b.x, b.y); u[3] = cvt_pk_bf16(b.z, b.w);
    return *(bf16x8*)u;
}

// ---------------- Kernel 1: mask branch -> mb[pix][p] ----------------------
// mb = colmean(pw_w) . gelu(dwconv3x3(mask)+dw_b)   (mean(pw_b) cancels)
// 1024 thr = 4 channel-quarters x 256 pixel-slots; LDS reduce over quarters.
__global__ __launch_bounds__(1024) void mask_kernel(const float* __restrict__ mask,
                                                    const float* __restrict__ dww,
                                                    const float* __restrict__ dwb,
                                                    const float* __restrict__ pww,
                                                    float* __restrict__ ws) {
    __shared__ float red[4][256][4];   // 16 KB
    __shared__ float cmS[64];
    int tid = threadIdx.x;
    if (tid < 64) {                    // fold colmean(pw_w) into this kernel
        float s = 0.f;
        for (int co = 0; co < 64; ++co) s += pww[co*64 + tid];
        cmS[tid] = s * (1.0f/64.0f);
    }
    __syncthreads();
    int bid = blockIdx.x;              // 256 blocks: [bp(16)][hgroup(16)]
    int bp = bid >> 4;
    int hg = bid & 15;
    int cq = tid >> 8;                 // channel quarter 0..3
    int t = tid & 255;                 // pixel slot: 8 rows x 32 colgroups
    int h = hg*8 + (t >> 5);
    int w0 = (t & 31) << 2;
    const float* mb_ = mask + (size_t)bp*64*HWSZ;
    int hm = h > 0 ? h-1 : 0;
    int hp = h < 127 ? h+1 : 127;
    float vt = h > 0 ? 1.f : 0.f;
    float vb = h < 127 ? 1.f : 0.f;
    float vl = w0 > 0 ? 1.f : 0.f;
    float vr = w0 < 124 ? 1.f : 0.f;
    int wl = w0 > 0 ? w0-1 : 0;
    int wr = w0 < 124 ? w0+4 : 127;
    float acc0=0.f, acc1=0.f, acc2=0.f, acc3=0.f;
    for (int ci = 0; ci < 16; ++ci) {
        int c = cq*16 + ci;
        const float* rc = mb_ + c*HWSZ;
        const float* r0 = rc + hm*WSZ;
        const float* r1 = rc + h*WSZ;
        const float* r2 = rc + hp*WSZ;
        float4 m0 = *(const float4*)(r0 + w0);
        float4 m1 = *(const float4*)(r1 + w0);
        float4 m2 = *(const float4*)(r2 + w0);
        float L0 = r0[wl]*vl, L1 = r1[wl]*vl, L2 = r2[wl]*vl;
        float R0 = r0[wr]*vr, R1 = r1[wr]*vr, R2 = r2[wr]*vr;
        float w00 = dww[c*9+0]*vt, w01 = dww[c*9+1]*vt, w02 = dww[c*9+2]*vt;
        float w10 = dww[c*9+3],    w11 = dww[c*9+4],    w12 = dww[c*9+5];
        float w20 = dww[c*9+6]*vb, w21 = dww[c*9+7]*vb, w22 = dww[c*9+8]*vb;
        float bb = dwb[c];
        float s0 = bb + w00*L0   + w01*m0.x + w02*m0.y
                      + w10*L1   + w11*m1.x + w12*m1.y
                      + w20*L2   + w21*m2.x + w22*m2.y;
        float s1 = bb + w00*m0.x + w01*m0.y + w02*m0.z
                      + w10*m1.x + w11*m1.y + w12*m1.z
                      + w20*m2.x + w21*m2.y + w22*m2.z;
        float s2 = bb + w00*m0.y + w01*m0.z + w02*m0.w
                      + w10*m1.y + w11*m1.z + w12*m1.w
                      + w20*m2.y + w21*m2.z + w22*m2.w;
        float s3 = bb + w00*m0.z + w01*m0.w + w02*R0
                      + w10*m1.z + w11*m1.w + w12*R1
                      + w20*m2.z + w21*m2.w + w22*R2;
        float cmc = cmS[c];
        acc0 += cmc * (0.5f*s0*(1.f + erff(s0*0.70710678118654752f)));
        acc1 += cmc * (0.5f*s1*(1.f + erff(s1*0.70710678118654752f)));
        acc2 += cmc * (0.5f*s2*(1.f + erff(s2*0.70710678118654752f)));
        acc3 += cmc * (0.5f*s3*(1.f + erff(s3*0.70710678118654752f)));
    }
    red[cq][t][0] = acc0;
    red[cq][t][1] = acc1;
    red[cq][t][2] = acc2;
    red[cq][t][3] = acc3;
    __syncthreads();
    if (tid < 256) {
        int b = bp >> 2, p = bp & 3;
        size_t base = (size_t)b*HWSZ + h*WSZ + w0;
        #pragma unroll
        for (int e = 0; e < 4; ++e) {
            float v = red[0][tid][e] + red[1][tid][e] + red[2][tid][e] + red[3][tid][e];
            ws[OFF_MB + (base+e)*4 + p] = v;
        }
    }
}

// ---------------- Kernel 2: MFMA qkv + attention + MFMA proj ---------------
__global__ __launch_bounds__(256) void attn_kernel(const float* __restrict__ x_in,
                                                   const float* __restrict__ wq,
                                                   const float* __restrict__ wk,
                                                   const float* __restrict__ wv,
                                                   const float* __restrict__ wp,
                                                   const float* __restrict__ bpj,
                                                   const float* __restrict__ rsc,
                                                   const float* __restrict__ ws,
                                                   float* __restrict__ out) {
    __shared__ u16 smem[32768];           // 64 KB
    u16* ldsA = smem;                     // 16 KB: x then y, swizzled A-frag order
    u16* ldsQ = smem + 8192;              // 16 KB: 32 tiles of qkv_idx layout
    u16* ldsK = smem + 16384;
    u16* ldsV = smem + 24576;
    float* outS = (float*)(smem + 8192);  // 32 KB fp32, overlays Q,K (phase 3)

    int t = threadIdx.x;
    int lane = t & 63;
    int wid = __builtin_amdgcn_readfirstlane(t >> 6);
    int n15 = lane & 15;
    int quad = lane >> 4;
    int b = blockIdx.x >> 9;              // 2048 blocks = 4 b x 512
    int hw0 = (blockIdx.x & 511) << 5;

    // B-fragments (bf16) for this wave's d-quarter
    bf16x8 fq0 = load_bfrag(wq, wid*16 + n15, quad*8);
    bf16x8 fq1 = load_bfrag(wq, wid*16 + n15, 32 + quad*8);
    bf16x8 fk0 = load_bfrag(wk, wid*16 + n15, quad*8);
    bf16x8 fk1 = load_bfrag(wk, wid*16 + n15, 32 + quad*8);
    bf16x8 fv0 = load_bfrag(wv, wid*16 + n15, quad*8);
    bf16x8 fv1 = load_bfrag(wv, wid*16 + n15, 32 + quad*8);
    bf16x8 fp0 = load_bfrag(wp, wid*16 + n15, quad*8);
    bf16x8 fp1 = load_bfrag(wp, wid*16 + n15, 32 + quad*8);
    float bias = bpj[wid*16 + n15];

    // stage x -> ldsA: c-pair u32 writes, packed converts, swizzled slots
    unsigned int* ldsA32 = (unsigned int*)ldsA;
    for (int it = 0; it < 4; ++it) {
        int i = t + (it << 8);            // 0..1023: [rowpair(128)][l4(8)]
        int rp = i >> 3, l4 = i & 7;
        int p = rp >> 5, cp = rp & 31;
        int c0 = cp*2;
        const float* r0 = x_in + (size_t)(b*256 + p*64 + c0)*HWSZ + hw0 + l4*4;
        float4 v0 = *(const float4*)r0;
        float4 v1 = *(const float4*)(r0 + HWSZ);
        int kt = c0 >> 5, qd = (c0 >> 3) & 3, j2 = (c0 & 7) >> 1;
        float a0[4] = {v0.x, v0.y, v0.z, v0.w};
        float a1[4] = {v1.x, v1.y, v1.z, v1.w};
        #pragma unroll
        for (int e = 0; e < 4; ++e) {
            int tau = (p << 5) + (l4 << 2) + e;
            int slot = (tau & 15) | (qd << 4);
            ldsA32[((tau >> 4)*2 + kt)*256 + sswz(slot)*4 + j2] = cvt_pk_bf16(a0[e], a1[e]);
        }
    }
    __syncthreads();

    // ---- phase 1: Q,K,V GEMMs ----
    int sl8 = sswz(lane)*8;
    for (int mt = 0; mt < 8; ++mt) {
        bf16x8 a0 = *(const bf16x8*)(ldsA + mt*1024 + sl8);
        bf16x8 a1 = *(const bf16x8*)(ldsA + mt*1024 + 512 + sl8);
        f32x4 aq = {0.f,0.f,0.f,0.f};
        f32x4 ak = {0.f,0.f,0.f,0.f};
        f32x4 av = {0.f,0.f,0.f,0.f};
        aq = __builtin_amdgcn_mfma_f32_16x16x32_bf16(a0, fq0, aq, 0, 0, 0);
        aq = __builtin_amdgcn_mfma_f32_16x16x32_bf16(a1, fq1, aq, 0, 0, 0);
        ak = __builtin_amdgcn_mfma_f32_16x16x32_bf16(a0, fk0, ak, 0, 0, 0);
        ak = __builtin_amdgcn_mfma_f32_16x16x32_bf16(a1, fk1, ak, 0, 0, 0);
        av = __builtin_amdgcn_mfma_f32_16x16x32_bf16(a0, fv0, av, 0, 0, 0);
        av = __builtin_amdgcn_mfma_f32_16x16x32_bf16(a1, fv1, av, 0, 0, 0);
        int tb = (mt*4 + wid)*256;        // C: col(n15)=d, row(quad*4+r)=token
        #pragma unroll
        for (int r = 0; r < 4; ++r) {
            int idx = tb + quad*64 + ((((r + quad) & 3)) << 4) + n15;
            ldsQ[idx] = f2bf_bits(aq[r]);
            ldsK[idx] = f2bf_bits(ak[r]);
            ldsV[idx] = f2bf_bits(av[r]);
        }
    }
    __syncthreads();

    // ---- phase 2: attention core (1 thread = 1 (pix, head)) ----
    {
        int pix = t & 31;
        int hd = t >> 5;
        float qv[4][8], kv[4][8], vv[4][8];
        #pragma unroll
        for (int p = 0; p < 4; ++p) {
            int tau = (p << 5) + pix;
            int base = ((tau >> 4)*4 + (hd >> 1))*256 + qkv_idx(tau & 15, (hd & 1)*8);
            bf16x8 q8 = *(const bf16x8*)(ldsQ + base);
            bf16x8 k8 = *(const bf16x8*)(ldsK + base);
            bf16x8 v8 = *(const bf16x8*)(ldsV + base);
            #pragma unroll
            for (int j = 0; j < 8; ++j) {
                qv[p][j] = bf2f((u16)q8[j]);
                kv[p][j] = bf2f((u16)k8[j]);
                vv[p][j] = bf2f((u16)v8[j]);
            }
        }
        #pragma unroll
        for (int p = 0; p < 4; ++p) {
            float sq = 0.f, sk = 0.f;
            #pragma unroll
            for (int j = 0; j < 8; ++j) { sq += qv[p][j]*qv[p][j]; sk += kv[p][j]*kv[p][j]; }
            float iq = 1.0f / fmaxf(sqrtf(sq), 1e-12f);
            float ik = 1.0f / fmaxf(sqrtf(sk), 1e-12f);
            #pragma unroll
            for (int j = 0; j < 8; ++j) { qv[p][j] *= iq; kv[p][j] *= ik; }
        }
        float4 mb4 = *(const float4*)(ws + OFF_MB + ((size_t)b*HWSZ + hw0 + pix)*4);
        float mba[4] = {mb4.x, mb4.y, mb4.z, mb4.w};
        float rs = rsc[hd];
        float at[4][4];
        #pragma unroll
        for (int p = 0; p < 4; ++p) {
            #pragma unroll
            for (int r = 0; r < 4; ++r) {
                float d = 0.f;
                #pragma unroll
                for (int j = 0; j < 8; ++j) d += qv[p][j]*kv[r][j];
                at[p][r] = d*rs + mba[r];   // -mb[p] cancels in softmax
            }
            float m = fmaxf(fmaxf(at[p][0], at[p][1]), fmaxf(at[p][2], at[p][3]));
            float e0 = expf(at[p][0]-m), e1 = expf(at[p][1]-m);
            float e2 = expf(at[p][2]-m), e3 = expf(at[p][3]-m);
            float inv = 1.0f / (e0+e1+e2+e3);
            at[p][0]=e0*inv; at[p][1]=e1*inv; at[p][2]=e2*inv; at[p][3]=e3*inv;
        }
        unsigned int* ldsA32w = (unsigned int*)ldsA;
        #pragma unroll
        for (int p = 0; p < 4; ++p) {
            float y[8];
            #pragma unroll
            for (int j = 0; j < 8; ++j) {
                y[j] = at[p][0]*vv[0][j] + at[p][1]*vv[1][j]
                     + at[p][2]*vv[2][j] + at[p][3]*vv[3][j];
            }
            int tau = (p << 5) + pix;      // y -> ldsA A-frag: d = hd*8+j
            int slot = (tau & 15) | ((hd & 3) << 4);
            unsigned int pk[4];
            pk[0] = cvt_pk_bf16(y[0], y[1]); pk[1] = cvt_pk_bf16(y[2], y[3]);
            pk[2] = cvt_pk_bf16(y[4], y[5]); pk[3] = cvt_pk_bf16(y[6], y[7]);
            *(uint4*)(ldsA32w + ((tau >> 4)*2 + (hd >> 2))*256 + sswz(slot)*4) = *(uint4*)pk;
        }
    }
    __syncthreads();

    // ---- phase 3: proj GEMM + bias, transpose via swizzled LDS ----
    for (int mt = 0; mt < 8; ++mt) {
        bf16x8 a0 = *(const bf16x8*)(ldsA + mt*1024 + sl8);
        bf16x8 a1 = *(const bf16x8*)(ldsA + mt*1024 + 512 + sl8);
        f32x4 ao = {0.f,0.f,0.f,0.f};
        ao = __builtin_amdgcn_mfma_f32_16x16x32_bf16(a0, fp0, ao, 0, 0, 0);
        ao = __builtin_amdgcn_mfma_f32_16x16x32_bf16(a1, fp1, ao, 0, 0, 0);
        #pragma unroll
        for (int r = 0; r < 4; ++r) {
            int tau = mt*16 + quad*4 + r;
            int d = wid*16 + n15;
            outS[tau*64 + (d ^ (tau & 31))] = ao[r] + bias;
        }
    }
    __syncthreads();
    for (int g = 0; g < 32; ++g) {
        int flat = (g << 8) + t;
        int px = flat & 31;
        int pd = flat >> 5;
        int d = pd & 63;
        int p = pd >> 6;
        int tau = (p << 5) + px;
        out[(size_t)((b*4 + p)*64 + d)*HWSZ + hw0 + px] = outS[tau*64 + (d ^ (tau & 31))];
    }
}

extern "C" void kernel_launch(void* const* d_in, const int* in_sizes, int n_in,
                              void* d_out, int out_size, void* d_ws, size_t ws_size,
                              hipStream_t stream) {
    const float* x_in  = (const float*)d_in[0];
    const float* mask  = (const float*)d_in[1];
    const float* wq    = (const float*)d_in[2];
    const float* wk    = (const float*)d_in[3];
    const float* wv    = (const float*)d_in[4];
    const float* wproj = (const float*)d_in[5];
    const float* bproj = (const float*)d_in[6];
    const float* resc  = (const float*)d_in[7];
    const float* dww   = (const float*)d_in[8];
    const float* dwb   = (const float*)d_in[9];
    const float* pww   = (const float*)d_in[10];
    float* ws = (float*)d_ws;
    float* outp = (float*)d_out;

    hipLaunchKernelGGL(mask_kernel, dim3(256), dim3(1024), 0, stream,
                       mask, dww, dwb, pww, ws);
    hipLaunchKernelGGL(attn_kernel, dim3(2048), dim3(256), 0, stream,
                       x_in, wq, wk, wv, wproj, bproj, resc, ws, outp);
}